// Round 14
// baseline (212.648 us; speedup 1.0000x reference)
//
#include <hip/hip_runtime.h>
#include <hip/hip_bf16.h>

typedef __attribute__((ext_vector_type(8))) short short8;
typedef __attribute__((ext_vector_type(4))) float floatx4;
typedef __attribute__((ext_vector_type(4))) unsigned uint4v;

#define B_ 8
#define C_IN 256
#define C_OUT 256
#define H_ 128
#define W_ 128
#define S_ 512
#define HW_ (H_*W_)
#define LIN_SCALE 0.04419417382415922f   /* 1/sqrt(512) */
#define CONV_SCALE 0.02083333333333333f  /* 1/sqrt(256*9) */
#define EPS_ 1e-8f

#define XPH 130          /* padded H: rows -1..128 -> 0..129 */
#define XPW 136          /* padded W: cols -1..134 -> 0..135 */
#define TTH 8            /* output tile 8h x 32w = 256 px */
#define TTW 32
#define PH2 10           /* halo patch 10 x 34 */
#define PW2 34
#define NPIX2 (PH2*PW2)  /* 340 live pixels */
#define BUFSZ 24576      /* 1536 items * 16 B per B LDS buffer */
#define NKB 72           /* 8 ci-chunks * 9 taps */
#define NTHR 256         /* 4 waves: 2(M) x 2(N) */

__device__ __forceinline__ unsigned short f2bf(float f) {
  unsigned u = __builtin_bit_cast(unsigned, f);
  u = (u + 0x7fffu + ((u >> 16) & 1u)) >> 16;
  return (unsigned short)u;
}
__device__ __forceinline__ unsigned pack2(float a, float b) {
  return (unsigned)f2bf(a) | ((unsigned)f2bf(b) << 16);
}
__device__ __forceinline__ void gload16(const void* g, void* l) {
  __builtin_amdgcn_global_load_lds(
      (const __attribute__((address_space(1))) unsigned*)g,
      (__attribute__((address_space(3))) unsigned*)l, 16, 0, 0);
}

// ---------------- kernel 1: style modulation s[b][ci] ----------------
__global__ void k_style(const float* __restrict__ style, const float* __restrict__ mw,
                        const float* __restrict__ mb, float* __restrict__ s) {
  __shared__ float sty[S_];
  const int b = blockIdx.x;
  for (int i = threadIdx.x; i < S_; i += 256) sty[i] = style[b*S_ + i];
  __syncthreads();
  const int ci = threadIdx.x;  // 256 threads
  const float* wr = mw + (size_t)ci*S_;
  float acc = 0.f;
  for (int i = 0; i < S_; ++i) acc += sty[i] * wr[i];
  s[b*C_IN + ci] = acc * LIN_SCALE + mb[ci];
}

// ---------------- kernel 2: demod[b][co] ----------------
__global__ void k_demod(const float* __restrict__ weight, const float* __restrict__ s,
                        float* __restrict__ demod) {
  const int b = blockIdx.x >> 8, co = blockIdx.x & 255;
  const int l = threadIdx.x;  // 64 threads
  const float* wrow = weight + (size_t)co*C_IN*9;
  const float* sb = s + b*C_IN;
  float acc = 0.f;
  for (int idx = l; idx < C_IN*9; idx += 64) {
    float wv = wrow[idx] * sb[idx/9];
    acc += wv*wv;
  }
#pragma unroll
  for (int off = 32; off; off >>= 1) acc += __shfl_down(acc, off, 64);
  if (l == 0) demod[blockIdx.x] = rsqrtf(acc * (CONV_SCALE*CONV_SCALE) + EPS_);
}

// ---------------- kernel 3: pack modulated weights into MFMA A-frag order ----
// One block per (b, chunk, mt), all 9 taps; contiguous 36 B weight-row reads.
// frag[((b*72 + kb)*16 + mt)*64 + lane][8], kb = chunk*9 + r;
// lane l: co = mt*16 + (l&15), ci = chunk*32 + (l>>4)*8 + j.
__global__ void k_pack(const float* __restrict__ weight, const float* __restrict__ s,
                       const float* __restrict__ demod, unsigned short* __restrict__ frag) {
  const int bid = blockIdx.x;            // b*128 + chunk*16 + mt
  const int mt = bid & 15;
  const int chunk = (bid >> 4) & 7;
  const int b  = bid >> 7;
  const int l = threadIdx.x;             // 64 threads
  const int co = mt*16 + (l & 15);
  const float dm = demod[b*C_OUT + co] * CONV_SCALE;
  const float* sb = s + b*C_IN;
  unsigned v[9][4];
#pragma unroll
  for (int jj = 0; jj < 4; ++jj) {
    int ci0 = chunk*32 + (l >> 4)*8 + jj*2;
    float w0[9], w1[9];
    __builtin_memcpy(w0, weight + ((size_t)co*C_IN + ci0    )*9, 36);
    __builtin_memcpy(w1, weight + ((size_t)co*C_IN + ci0 + 1)*9, 36);
    float s0 = sb[ci0] * dm, s1 = sb[ci0 + 1] * dm;
#pragma unroll
    for (int r = 0; r < 9; ++r)
      v[r][jj] = pack2(w0[r]*s0, w1[r]*s1);
  }
#pragma unroll
  for (int r = 0; r < 9; ++r) {
    unsigned* dst = (unsigned*)(frag +
        ((size_t)((b*NKB + chunk*9 + r)*16 + mt))*512 + l*8);
    dst[0] = v[r][0]; dst[1] = v[r][1]; dst[2] = v[r][2]; dst[3] = v[r][3];
  }
}

// ---------------- kernel 3c: NCHW f32 -> chunk-major padded bf16 + border ----
__global__ void k_xpose(const float* __restrict__ x, unsigned short* __restrict__ xp) {
  __shared__ __align__(16) unsigned lds32[64*128];   // 32 KB
  const int bid = blockIdx.x;          // 8b * 128h * 2
  const int half = bid & 1, h = (bid >> 1) & 127, b = bid >> 8;
  const int w0 = half*64;
  const int t = threadIdx.x;
  const uint4v z = {0u,0u,0u,0u};
  if (t < 32) {
    int chunk = t >> 2, part = t & 3;
    unsigned short* p = xp +
        (((size_t)(b*8 + chunk)*XPH + (h + 1))*XPW + half*129)*32 + part*8;
    *(uint4v*)p = z;
  }
  if (h == 0) {
    for (int i = t; i < 65*2*8*4; i += 256) {
      int part = i & 3, cell = i >> 2;
      int wwi = cell % 65; int rest = cell / 65;
      int rowsel = rest & 1, chunk = rest >> 1;
      unsigned short* p = xp +
          (((size_t)(b*8 + chunk)*XPH + rowsel*129)*XPW + (half*65 + wwi))*32 + part*8;
      *(uint4v*)p = z;
    }
  }
  const float* xr = x + (size_t)b*C_IN*HW_ + (size_t)h*W_ + w0;
#pragma unroll
  for (int j = 0; j < 8; ++j) {
    int cp = j*16 + (t >> 4);          // ci-pair 0..127
    int ci = cp*2;
    const float* p0 = xr + (size_t)ci*HW_ + (t & 15)*4;
    floatx4 f0 = *(const floatx4*)p0;
    floatx4 f1 = *(const floatx4*)(p0 + HW_);
    int g = cp >> 2, slot = cp & 3;
#pragma unroll
    for (int k = 0; k < 4; ++k) {
      int px = (t & 15)*4 + k;
      lds32[px*128 + ((g ^ ((px >> 2) & 7)) << 2) + slot] = pack2(f0[k], f1[k]);
    }
  }
  __syncthreads();
#pragma unroll
  for (int i = 0; i < 8; ++i) {
    int item = i*256 + t;
    int px = item >> 5, g = item & 31;
    int c = (item >> 2) & 7, sub = item & 3;
    int gs = g ^ ((px >> 2) & 7);
    uint4v v = *(const uint4v*)&lds32[px*128 + (gs << 2)];
    unsigned short* dst = xp +
        (((size_t)(b*8 + c)*XPH + (h + 1))*XPW + (w0 + 1 + px))*32 + sub*8;
    *(uint4v*)dst = v;
  }
}

// ---------------- kernel 4: implicit-GEMM conv ----------------
// A OFF the LDS pipe: A-frags load global(L2-hot) -> registers, 2-deep pa/pb
// rotation (compiler emits precise counted vmcnt for reg loads). Per step the
// issue order is A-loads THEN the B gload_lds piece (B always YOUNGER than any
// awaited A -> A-waits leave B staging in flight; the round-6 entanglement is
// structurally impossible). B: LDS double-buffer, async gload_lds, linear dest,
// pre-swizzled source, Br[8] read-ahead (the round-12 win, kept).
// Barriers 72 -> 16/block: MIDBAR at step-8 start (vmcnt(4): FIFO-audited to
// force B@5.. complete, A@7 stays in flight) protects the cross-wave read of
// next chunk's B; plain boundary barrier protects the buffer swap (WAR).
// LDS/CU-step demand drops 96->64 KB (753 cyc) < MFMA demand (1033 cyc):
// MFMA becomes the binding pipe.
__launch_bounds__(NTHR, 2)
__global__ void k_conv(const unsigned short* __restrict__ xpad,
                       const unsigned short* __restrict__ frag,
                       float* __restrict__ out) {
  __shared__ __align__(16) unsigned char sm[2*BUFSZ];   // 49152 B
  const int work = (blockIdx.x & 7)*128 + (blockIdx.x >> 3);  // XCD x <- batch x
  const int ct = work & 1;
  const int w2 = work >> 1;
  const int sx = w2 & 3, sy = (w2 >> 2) & 15, b = w2 >> 6;
  const int h0 = sy*TTH, w0 = sx*TTW;
  const int tid = threadIdx.x;
  const int lane = tid & 63, wv = tid >> 6;
  const int wm = wv >> 1, wn = wv & 1;
  const int sl = lane >> 4, c15 = lane & 15, wn8 = wn*8;
  const int b8 = b*8;

  floatx4 acc[4][8];
#pragma unroll
  for (int m = 0; m < 4; ++m)
#pragma unroll
    for (int n = 0; n < 8; ++n) acc[m][n] = floatx4{0.f, 0.f, 0.f, 0.f};

  int srcoff[6];
#pragma unroll
  for (int p = 0; p < 6; ++p) {
    int item = p*256 + tid;
    int px = item >> 2, q8s = item & 3;
    if (px > NPIX2 - 1) px = NPIX2 - 1;        // SOURCE clamp; dest stays linear
    int ph = px / PW2, pw = px - ph*PW2;
    int q8 = q8s ^ ((px >> 1) & 3);            // pre-swizzled SOURCE (rule #21)
    srcoff[p] = (ph*XPW + pw)*32 + q8*8;
  }
  // per-wave A base: this wave's 4 mt-frags of kb=0, this lane
  const unsigned short* abase = frag +
      ((size_t)b*NKB*16 + ct*8 + wm*4)*512 + (size_t)lane*8;

  short8 pa[4], pb[4], Br[8];

  auto loadA = [&](short8* dst, int kb) __attribute__((always_inline)) {
    const unsigned short* src = abase + (size_t)kb*8192;
    dst[0] = *(const short8*)(src);
    dst[1] = *(const short8*)(src + 512);
    dst[2] = *(const short8*)(src + 1024);
    dst[3] = *(const short8*)(src + 1536);
  };
  auto readBr = [&](int bbase, int tap) __attribute__((always_inline)) {
    const int dh = tap/3, dw = tap%3;
#pragma unroll
    for (int n = 0; n < 8; ++n) {
      int nt = wn8 + n;
      int pix = ((nt >> 1) + dh)*PW2 + ((nt & 1)*16 + c15 + dw);
      int addr = pix*64 + ((sl ^ ((pix >> 1) & 3)) << 4);
      Br[n] = *(const short8*)(sm + bbase + addr);
    }
  };
  auto mfmaStep = [&](const short8* A) __attribute__((always_inline)) {
    __builtin_amdgcn_s_setprio(1);
#pragma unroll
    for (int n = 0; n < 8; ++n) {
      acc[0][n] = __builtin_amdgcn_mfma_f32_16x16x32_bf16(A[0], Br[n], acc[0][n], 0, 0, 0);
      acc[1][n] = __builtin_amdgcn_mfma_f32_16x16x32_bf16(A[1], Br[n], acc[1][n], 0, 0, 0);
      acc[2][n] = __builtin_amdgcn_mfma_f32_16x16x32_bf16(A[2], Br[n], acc[2][n], 0, 0, 0);
      acc[3][n] = __builtin_amdgcn_mfma_f32_16x16x32_bf16(A[3], Br[n], acc[3][n], 0, 0, 0);
    }
    __builtin_amdgcn_s_setprio(0);
  };

#define SBAR0 __builtin_amdgcn_sched_barrier(0)
// MIDBAR (step-8 start): vmcnt(4) allows only A@7 outstanding -> forces all
// B(c+1) pieces (issued steps 0-5, older) complete; barrier publishes LDS.
#define MIDBAR do { SBAR0; \
    asm volatile("s_waitcnt vmcnt(4)" ::: "memory"); \
    __builtin_amdgcn_s_barrier(); SBAR0; } while (0)

// STEP(J,R): [A-loads for step g+1 into opposite buffer] [B piece R -> bs]
// [MFMA on current buffer] [ds_read Br for step g+1].
// Current A buffer parity: (J+R)&1 == 0 -> pa. R==8 reads next chunk's B.
#define STEP(J, R) do { \
    SBAR0; \
    { int kbs = c9 + (R) + 1; if (kbs > NKB-1) kbs = NKB-1; \
      loadA((((J)+(R)) & 1) ? pa : pb, kbs); } \
    if ((R) < 6 && c < 7) \
      gload16(xc + srcoff[R], sm + ((((J)+1)&1)*BUFSZ) + ((R)*256 + tid)*16); \
    mfmaStep((((J)+(R)) & 1) ? pb : pa); \
    readBr((((R)==8) ? (((J)+1)&1) : ((J)&1))*BUFSZ, ((R)==8) ? 0 : (R)+1); \
  } while (0)

#define CHUNK(J) do { \
    const int c = cc*4 + (J); const int c9 = c*9; \
    const int cn = (c < 7) ? c + 1 : 7; \
    const unsigned short* xc = xpad + (((size_t)(b8 + cn)*XPH + h0)*XPW + w0)*32; \
    STEP(J,0); STEP(J,1); STEP(J,2); STEP(J,3); \
    STEP(J,4); STEP(J,5); STEP(J,6); STEP(J,7); \
    MIDBAR; \
    STEP(J,8); \
    if (c < 7) { SBAR0; __builtin_amdgcn_s_barrier(); SBAR0; } \
  } while (0)

  // prologue: B(0) 6 pieces -> b0; A(0) -> pa; drain all; read Br for step 0.
  {
    const unsigned short* xc0 = xpad + (((size_t)b8*XPH + h0)*XPW + w0)*32;
#pragma unroll
    for (int p = 0; p < 6; ++p)
      gload16(xc0 + srcoff[p], sm + (p*256 + tid)*16);
    loadA(pa, 0);
    SBAR0;
    asm volatile("s_waitcnt vmcnt(0)" ::: "memory");
    __builtin_amdgcn_s_barrier();
    SBAR0;
    readBr(0, 0);
  }

#pragma unroll 1
  for (int cc = 0; cc < 2; ++cc) {
    CHUNK(0); CHUNK(1); CHUNK(2); CHUNK(3);
  }
#undef CHUNK
#undef STEP
#undef MIDBAR
#undef SBAR0

  // epilogue: C/D col=lane&15 (pixel w), row=(lane>>4)*4+i (co)
  float* ob = out + ((size_t)b*C_OUT + ct*128)*HW_;
  const int tw = lane & 15, rg = lane >> 4;
#pragma unroll
  for (int m = 0; m < 4; ++m) {
#pragma unroll
    for (int n = 0; n < 8; ++n) {
      int co = (wm*4 + m)*16 + rg*4;
      int nt = wn8 + n;
      int h = h0 + (nt >> 1);
      int w = w0 + (nt & 1)*16 + tw;
      float* p = ob + (size_t)co*HW_ + (size_t)h*W_ + w;
#pragma unroll
      for (int i = 0; i < 4; ++i) p[i*HW_] = acc[m][n][i];
    }
  }
}

extern "C" void kernel_launch(void* const* d_in, const int* in_sizes, int n_in,
                              void* d_out, int out_size, void* d_ws, size_t ws_size,
                              hipStream_t stream) {
  const float* x      = (const float*)d_in[0];
  const float* style  = (const float*)d_in[1];
  const float* weight = (const float*)d_in[2];
  const float* mod_w  = (const float*)d_in[3];
  const float* mod_b  = (const float*)d_in[4];
  float* out = (float*)d_out;
  char* ws = (char*)d_ws;

  float* s     = (float*)ws;                            // 8 KB
  float* demod = (float*)(ws + 8192);                   // 8 KB
  unsigned short* frag = (unsigned short*)(ws + 16384); // 9.44 MB
  unsigned short* xpad = (unsigned short*)(ws + (16u<<20)); // 72.4 MB chunk-major bf16

  k_style<<<B_, 256, 0, stream>>>(style, mod_w, mod_b, s);
  k_demod<<<B_*C_OUT, 64, 0, stream>>>(weight, s, demod);
  k_pack<<<B_*8*16, 64, 0, stream>>>(weight, s, demod, frag);
  k_xpose<<<B_*H_*2, 256, 0, stream>>>(x, xpad);
  k_conv<<<B_*2*16*4, NTHR, 0, stream>>>(xpad, frag, out);
}

// Round 15
// 193.341 us; speedup vs baseline: 1.0999x; 1.0999x over previous
//
#include <hip/hip_runtime.h>
#include <hip/hip_bf16.h>

typedef __attribute__((ext_vector_type(8))) short short8;
typedef __attribute__((ext_vector_type(4))) float floatx4;
typedef __attribute__((ext_vector_type(4))) unsigned uint4v;

#define B_ 8
#define C_IN 256
#define C_OUT 256
#define H_ 128
#define W_ 128
#define S_ 512
#define HW_ (H_*W_)
#define LIN_SCALE 0.04419417382415922f   /* 1/sqrt(512) */
#define CONV_SCALE 0.02083333333333333f  /* 1/sqrt(256*9) */
#define EPS_ 1e-8f

#define XPH 130          /* padded H: rows -1..128 -> 0..129 */
#define XPW 136          /* padded W: cols -1..134 -> 0..135 */
#define TTH 8            /* output tile 8h x 32w = 256 px */
#define TTW 32
#define PH2 10           /* halo patch 10 x 34 */
#define PW2 34
#define NPIX2 (PH2*PW2)  /* 340 live pixels */
#define BUFSZ 24576      /* 1536 items * 16 B per B LDS buffer */
#define ABUFSZ 8192      /* 8 mt-frags * 1 KB per A LDS buffer */
#define ABASE_LDS 49152  /* A buffers at sm+49152 */
#define NKB 72           /* 8 ci-chunks * 9 taps */
#define NTHR 256         /* 4 waves: 2(M) x 2(N) */

__device__ __forceinline__ unsigned short f2bf(float f) {
  unsigned u = __builtin_bit_cast(unsigned, f);
  u = (u + 0x7fffu + ((u >> 16) & 1u)) >> 16;
  return (unsigned short)u;
}
__device__ __forceinline__ unsigned pack2(float a, float b) {
  return (unsigned)f2bf(a) | ((unsigned)f2bf(b) << 16);
}
__device__ __forceinline__ void gload16(const void* g, void* l) {
  __builtin_amdgcn_global_load_lds(
      (const __attribute__((address_space(1))) unsigned*)g,
      (__attribute__((address_space(3))) unsigned*)l, 16, 0, 0);
}

// ---------------- kernel 1: style modulation s[b][ci] ----------------
__global__ void k_style(const float* __restrict__ style, const float* __restrict__ mw,
                        const float* __restrict__ mb, float* __restrict__ s) {
  __shared__ float sty[S_];
  const int b = blockIdx.x;
  for (int i = threadIdx.x; i < S_; i += 256) sty[i] = style[b*S_ + i];
  __syncthreads();
  const int ci = threadIdx.x;  // 256 threads
  const float* wr = mw + (size_t)ci*S_;
  float acc = 0.f;
  for (int i = 0; i < S_; ++i) acc += sty[i] * wr[i];
  s[b*C_IN + ci] = acc * LIN_SCALE + mb[ci];
}

// ---------------- kernel 2: fused demod + pack ----------------
// One block per (b, mt): phase 1 computes demod for the block's 16 co via a
// 16x16 block reduction (contiguous 576 B weight slices); phase 2 packs all
// 8 chunks x 9 taps for those co (each wave owns 2 chunks; round-13 k_pack
// inner loop). Removes the k_demod launch + demod global round-trip.
// frag[((b*72 + kb)*16 + mt)*64 + lane][8], kb = chunk*9 + r;
// lane l: co = mt*16 + (l&15), ci = chunk*32 + (l>>4)*8 + j.
__global__ void k_dpack(const float* __restrict__ weight, const float* __restrict__ s,
                        unsigned short* __restrict__ frag) {
  __shared__ float red[16][17];
  __shared__ float dmS[16];
  const int mt = blockIdx.x & 15, b = blockIdx.x >> 4;
  const int tid = threadIdx.x;
  const float* sb = s + b*C_IN;
  {  // demod phase: co = mt*16 + (tid&15), ci-slice = tid>>4 (16 ci each)
    const int co = mt*16 + (tid & 15);
    const int slice = tid >> 4;
    const float* wr = weight + ((size_t)co*C_IN + slice*16)*9;
    float acc = 0.f;
#pragma unroll
    for (int i = 0; i < 16; ++i) {
      float sv = sb[slice*16 + i];
#pragma unroll
      for (int r = 0; r < 9; ++r) { float wv = wr[i*9 + r]*sv; acc += wv*wv; }
    }
    red[slice][tid & 15] = acc;
  }
  __syncthreads();
  if (tid < 16) {
    float a = 0.f;
#pragma unroll
    for (int sl = 0; sl < 16; ++sl) a += red[sl][tid];
    dmS[tid] = rsqrtf(a*(CONV_SCALE*CONV_SCALE) + EPS_) * CONV_SCALE;
  }
  __syncthreads();
  // pack phase: wave wv handles chunks {wv, wv+4}
  const int lane = tid & 63, wv = tid >> 6;
  const int co = mt*16 + (lane & 15);
  const float dm = dmS[lane & 15];
#pragma unroll
  for (int cc = 0; cc < 2; ++cc) {
    const int chunk = wv + cc*4;
    unsigned v[9][4];
#pragma unroll
    for (int jj = 0; jj < 4; ++jj) {
      int ci0 = chunk*32 + (lane >> 4)*8 + jj*2;
      float w0[9], w1[9];
      __builtin_memcpy(w0, weight + ((size_t)co*C_IN + ci0    )*9, 36);
      __builtin_memcpy(w1, weight + ((size_t)co*C_IN + ci0 + 1)*9, 36);
      float s0 = sb[ci0] * dm, s1 = sb[ci0 + 1] * dm;
#pragma unroll
      for (int r = 0; r < 9; ++r)
        v[r][jj] = pack2(w0[r]*s0, w1[r]*s1);
    }
#pragma unroll
    for (int r = 0; r < 9; ++r) {
      unsigned* dst = (unsigned*)(frag +
          ((size_t)((b*NKB + chunk*9 + r)*16 + mt))*512 + lane*8);
      dst[0] = v[r][0]; dst[1] = v[r][1]; dst[2] = v[r][2]; dst[3] = v[r][3];
    }
  }
}

// ---------------- kernel 3c: NCHW f32 -> chunk-major padded bf16 + border ----
__global__ void k_xpose(const float* __restrict__ x, unsigned short* __restrict__ xp) {
  __shared__ __align__(16) unsigned lds32[64*128];   // 32 KB
  const int bid = blockIdx.x;          // 8b * 128h * 2
  const int half = bid & 1, h = (bid >> 1) & 127, b = bid >> 8;
  const int w0 = half*64;
  const int t = threadIdx.x;
  const uint4v z = {0u,0u,0u,0u};
  if (t < 32) {
    int chunk = t >> 2, part = t & 3;
    unsigned short* p = xp +
        (((size_t)(b*8 + chunk)*XPH + (h + 1))*XPW + half*129)*32 + part*8;
    *(uint4v*)p = z;
  }
  if (h == 0) {
    for (int i = t; i < 65*2*8*4; i += 256) {
      int part = i & 3, cell = i >> 2;
      int wwi = cell % 65; int rest = cell / 65;
      int rowsel = rest & 1, chunk = rest >> 1;
      unsigned short* p = xp +
          (((size_t)(b*8 + chunk)*XPH + rowsel*129)*XPW + (half*65 + wwi))*32 + part*8;
      *(uint4v*)p = z;
    }
  }
  const float* xr = x + (size_t)b*C_IN*HW_ + (size_t)h*W_ + w0;
#pragma unroll
  for (int j = 0; j < 8; ++j) {
    int cp = j*16 + (t >> 4);          // ci-pair 0..127
    int ci = cp*2;
    const float* p0 = xr + (size_t)ci*HW_ + (t & 15)*4;
    floatx4 f0 = *(const floatx4*)p0;
    floatx4 f1 = *(const floatx4*)(p0 + HW_);
    int g = cp >> 2, slot = cp & 3;
#pragma unroll
    for (int k = 0; k < 4; ++k) {
      int px = (t & 15)*4 + k;
      lds32[px*128 + ((g ^ ((px >> 2) & 7)) << 2) + slot] = pack2(f0[k], f1[k]);
    }
  }
  __syncthreads();
#pragma unroll
  for (int i = 0; i < 8; ++i) {
    int item = i*256 + t;
    int px = item >> 5, g = item & 31;
    int c = (item >> 2) & 7, sub = item & 3;
    int gs = g ^ ((px >> 2) & 7);
    uint4v v = *(const uint4v*)&lds32[px*128 + (gs << 2)];
    unsigned short* dst = xp +
        (((size_t)(b*8 + c)*XPH + (h + 1))*XPW + (w0 + 1 + px))*32 + sub*8;
    *(uint4v*)dst = v;
  }
}

// ---------------- kernel 4: implicit-GEMM conv (round-13 verbatim) ----------
// Counted-vmcnt raw barriers, async gload_lds, linear dests, pre-swizzled
// sources, Ar/Br read-ahead regs, 4 A-slots staged 3 ahead; vmcnt table
// {2,3,4,4,4,4,4,3,2}. Validated: 112.4 us, MfmaUtil 62.5%, 0 conflicts,
// 0 spill. r6/r10/r14 all showed every other A-path loses — do not touch.
__launch_bounds__(NTHR, 2)
__global__ void k_conv(const unsigned short* __restrict__ xpad,
                       const unsigned short* __restrict__ frag,
                       float* __restrict__ out) {
  __shared__ __align__(16) unsigned char sm[2*BUFSZ + 4*ABUFSZ];  // 81920 B
  const int work = (blockIdx.x & 7)*128 + (blockIdx.x >> 3);  // XCD x <- batch x
  const int ct = work & 1;
  const int w2 = work >> 1;
  const int sx = w2 & 3, sy = (w2 >> 2) & 15, b = w2 >> 6;
  const int h0 = sy*TTH, w0 = sx*TTW;
  const int tid = threadIdx.x;
  const int lane = tid & 63, wv = tid >> 6;
  const int wm = wv >> 1, wn = wv & 1;
  const int sl = lane >> 4, c15 = lane & 15, wn8 = wn*8;
  const int b8 = b*8;

  floatx4 acc[4][8];
#pragma unroll
  for (int m = 0; m < 4; ++m)
#pragma unroll
    for (int n = 0; n < 8; ++n) acc[m][n] = floatx4{0.f, 0.f, 0.f, 0.f};

  int srcoff[6];
#pragma unroll
  for (int p = 0; p < 6; ++p) {
    int item = p*256 + tid;
    int px = item >> 2, q8s = item & 3;
    if (px > NPIX2 - 1) px = NPIX2 - 1;        // SOURCE clamp; dest stays linear
    int ph = px / PW2, pw = px - ph*PW2;
    int q8 = q8s ^ ((px >> 1) & 3);            // pre-swizzled SOURCE (rule #21)
    srcoff[p] = (ph*XPW + pw)*32 + q8*8;
  }
  const unsigned short* abase = frag + ((size_t)b*NKB*16 + ct*8)*512 + (size_t)tid*8;
  const unsigned char* aRd = sm + ABASE_LDS + wm*4096 + lane*16;

  short8 Ar[4], Br[8];

  auto readRegs = [&](int slot, int bbase, int tap) __attribute__((always_inline)) {
    const int dh = tap/3, dw = tap%3;
#pragma unroll
    for (int m = 0; m < 4; ++m)
      Ar[m] = *(const short8*)(aRd + slot*8192 + m*1024);
#pragma unroll
    for (int n = 0; n < 8; ++n) {
      int nt = wn8 + n;
      int pix = ((nt >> 1) + dh)*PW2 + ((nt & 1)*16 + c15 + dw);
      int addr = pix*64 + ((sl ^ ((pix >> 1) & 3)) << 4);
      Br[n] = *(const short8*)(sm + bbase + addr);
    }
  };
  auto mfmaStep = [&]() __attribute__((always_inline)) {
    __builtin_amdgcn_s_setprio(1);
#pragma unroll
    for (int n = 0; n < 8; ++n) {
      acc[0][n] = __builtin_amdgcn_mfma_f32_16x16x32_bf16(Ar[0], Br[n], acc[0][n], 0, 0, 0);
      acc[1][n] = __builtin_amdgcn_mfma_f32_16x16x32_bf16(Ar[1], Br[n], acc[1][n], 0, 0, 0);
      acc[2][n] = __builtin_amdgcn_mfma_f32_16x16x32_bf16(Ar[2], Br[n], acc[2][n], 0, 0, 0);
      acc[3][n] = __builtin_amdgcn_mfma_f32_16x16x32_bf16(Ar[3], Br[n], acc[3][n], 0, 0, 0);
    }
    __builtin_amdgcn_s_setprio(0);
  };

#define SBAR0 __builtin_amdgcn_sched_barrier(0)
#define WAITB(NLIT) do { SBAR0; \
    asm volatile("s_waitcnt vmcnt(" NLIT ")" ::: "memory"); \
    __builtin_amdgcn_s_barrier(); SBAR0; } while (0)

#define STEP(J, R, NLIT) do { \
    WAITB(NLIT); \
    { int kbs = c9 + (R) + 3; if (kbs > NKB-1) kbs = NKB-1; \
      const unsigned short* asrc = abase + (size_t)kbs*8192; \
      unsigned char* adst = sm + ABASE_LDS + ((((J)+(R)+3)&3)*8192) + tid*16; \
      gload16(asrc, adst); gload16(asrc + 2048, adst + 4096); } \
    if ((R) < 6) \
      gload16(xc + srcoff[R], sm + ((((J)+1)&1)*BUFSZ) + ((R)*256 + tid)*16); \
    mfmaStep(); \
    readRegs(((J)+(R)+1)&3, \
             ((R)==8) ? ((((J)+1)&1)*BUFSZ) : (((J)&1)*BUFSZ), \
             ((R)==8) ? 0 : (R)+1); \
  } while (0)

#define CHUNK(J) do { \
    const int c = cc*4 + (J); const int c9 = c*9; \
    const int cn = (c < 7) ? c + 1 : 7; \
    const unsigned short* xc = xpad + (((size_t)(b8 + cn)*XPH + h0)*XPW + w0)*32; \
    STEP(J,0,"2"); STEP(J,1,"3"); STEP(J,2,"4"); \
    STEP(J,3,"4"); STEP(J,4,"4"); STEP(J,5,"4"); \
    STEP(J,6,"4"); STEP(J,7,"3"); STEP(J,8,"2"); \
  } while (0)

  // prologue: B(0) 6 pieces -> b0; A(0,1,2) -> slots 0,1,2; drain; read step0
  {
    const unsigned short* xc0 = xpad + (((size_t)b8*XPH + h0)*XPW + w0)*32;
#pragma unroll
    for (int p = 0; p < 6; ++p)
      gload16(xc0 + srcoff[p], sm + (p*256 + tid)*16);
#pragma unroll
    for (int s5 = 0; s5 < 3; ++s5) {
      const unsigned short* asrc = abase + (size_t)s5*8192;
      unsigned char* adst = sm + ABASE_LDS + s5*8192 + tid*16;
      gload16(asrc, adst); gload16(asrc + 2048, adst + 4096);
    }
    SBAR0;
    asm volatile("s_waitcnt vmcnt(0)" ::: "memory");
    __builtin_amdgcn_s_barrier();
    SBAR0;
    readRegs(0, 0, 0);
  }

#pragma unroll 1
  for (int cc = 0; cc < 2; ++cc) {
    CHUNK(0); CHUNK(1); CHUNK(2); CHUNK(3);
  }
#undef CHUNK
#undef STEP
#undef WAITB
#undef SBAR0

  // epilogue: C/D col=lane&15 (pixel w), row=(lane>>4)*4+i (co)
  float* ob = out + ((size_t)b*C_OUT + ct*128)*HW_;
  const int tw = lane & 15, rg = lane >> 4;
#pragma unroll
  for (int m = 0; m < 4; ++m) {
#pragma unroll
    for (int n = 0; n < 8; ++n) {
      int co = (wm*4 + m)*16 + rg*4;
      int nt = wn8 + n;
      int h = h0 + (nt >> 1);
      int w = w0 + (nt & 1)*16 + tw;
      float* p = ob + (size_t)co*HW_ + (size_t)h*W_ + w;
#pragma unroll
      for (int i = 0; i < 4; ++i) p[i*HW_] = acc[m][n][i];
    }
  }
}

extern "C" void kernel_launch(void* const* d_in, const int* in_sizes, int n_in,
                              void* d_out, int out_size, void* d_ws, size_t ws_size,
                              hipStream_t stream) {
  const float* x      = (const float*)d_in[0];
  const float* style  = (const float*)d_in[1];
  const float* weight = (const float*)d_in[2];
  const float* mod_w  = (const float*)d_in[3];
  const float* mod_b  = (const float*)d_in[4];
  float* out = (float*)d_out;
  char* ws = (char*)d_ws;

  float* s     = (float*)ws;                            // 8 KB
  unsigned short* frag = (unsigned short*)(ws + 16384); // 9.44 MB
  unsigned short* xpad = (unsigned short*)(ws + (16u<<20)); // 72.4 MB chunk-major bf16

  k_style<<<B_, 256, 0, stream>>>(style, mod_w, mod_b, s);
  k_dpack<<<B_*16, 256, 0, stream>>>(weight, s, frag);
  k_xpose<<<B_*H_*2, 256, 0, stream>>>(x, xpad);
  k_conv<<<B_*2*16*4, NTHR, 0, stream>>>(xpad, frag, out);
}